// Round 6
// baseline (224.283 us; speedup 1.0000x reference)
//
#include <hip/hip_runtime.h>
#include <stdint.h>

#define N_VOX   (1 << 19)
#define CIN     64
#define COUT    128
#define BIN_SHIFT 6
#define BINS    (1 << 17)
#define EPSV    1e-5f

typedef float f32x4 __attribute__((ext_vector_type(4)));
typedef float f32x2 __attribute__((ext_vector_type(2)));

static __device__ __forceinline__ void nt_store4(float* p, f32x4 v) {
    __builtin_nontemporal_store(v, (f32x4*)p);
}
static __device__ __forceinline__ void nt_store2(float* p, f32x2 v) {
    __builtin_nontemporal_store(v, (f32x2*)p);
}

// d_out: out_f [N,128] f32, then new_idx [N,4] f32.
// valid row <=> (lin & 0x201)==0 (y%2==0 && x%2==0).
// ws ints: hist[BINS] | vcount(+3) | cursor[BINS] | packed[N] | perm[N]
//          | vlist[N] | partials[128]

// custom clear: rocclr fillBuffer took 162 us for 512 KB (tiny grid).
// 129 blocks x 256 thr x int4 = 528 KB in a few us.
__global__ void k_clear(int* __restrict__ p) {
    int t = blockIdx.x * 256 + threadIdx.x;
    if (t < (BINS + 4) / 4 + 1) {
        int4 z = make_int4(0, 0, 0, 0);
        *(int4*)&p[t * 4] = z;
    }
}

__global__ void k_hist(const int* __restrict__ idx, unsigned* __restrict__ packed,
                       int* __restrict__ hist) {
    int j = blockIdx.x * 256 + threadIdx.x;
    int4 v = *(const int4*)&idx[j * 4];
    int lin = ((v.x * 8 + v.y) * 512 + v.z) * 512 + v.w;
    int off = atomicAdd(&hist[lin >> BIN_SHIFT], 1);
    packed[j] = ((unsigned)lin << 9) | (unsigned)off;   // off < 512 (Poisson λ=4)
}

__global__ void scan_partial(const int* __restrict__ hist, int* __restrict__ partials) {
    __shared__ int sdata[256];
    int base = blockIdx.x * 1024;
    int t = threadIdx.x;
    int s = hist[base + t] + hist[base + t + 256] + hist[base + t + 512] + hist[base + t + 768];
    sdata[t] = s;
    __syncthreads();
    for (int off = 128; off > 0; off >>= 1) {
        if (t < off) sdata[t] += sdata[t + off];
        __syncthreads();
    }
    if (t == 0) partials[blockIdx.x] = sdata[0];
}

__global__ void scan_top(int* __restrict__ partials) {
    __shared__ int sdata[128];
    int t = threadIdx.x;
    sdata[t] = partials[t];
    __syncthreads();
    for (int off = 1; off < 128; off <<= 1) {
        int v = 0;
        if (t >= off) v = sdata[t - off];
        __syncthreads();
        sdata[t] += v;
        __syncthreads();
    }
    partials[t] = t ? sdata[t - 1] : 0;
}

__global__ void scan_final(const int* __restrict__ hist, const int* __restrict__ partials,
                           int* __restrict__ cursor) {
    __shared__ int sscan[256];
    int t = threadIdx.x;
    int base = blockIdx.x * 1024 + t * 4;
    int4 v = *(const int4*)&hist[base];
    int s0 = v.x, s1 = v.x + v.y, s2 = s1 + v.z, s3 = s2 + v.w;
    sscan[t] = s3;
    __syncthreads();
    for (int off = 1; off < 256; off <<= 1) {
        int u = 0;
        if (t >= off) u = sscan[t - off];
        __syncthreads();
        sscan[t] += u;
        __syncthreads();
    }
    int prefix = partials[blockIdx.x] + (t ? sscan[t - 1] : 0);
    int4 e;
    e.x = prefix;
    e.y = prefix + s0;
    e.z = prefix + s1;
    e.w = prefix + s2;
    *(int4*)&cursor[base] = e;   // cursor = bin start, never modified after
}

__global__ void k_scatter(const unsigned* __restrict__ packed, const int* __restrict__ cursor,
                          int* __restrict__ perm) {
    int j = blockIdx.x * 256 + threadIdx.x;
    unsigned p = packed[j];
    int pos = cursor[p >> (9 + BIN_SHIFT)] + (int)(p & 0x1FFu);
    perm[pos] = j;
}

__global__ void k_fixup(const int* __restrict__ hist, const int* __restrict__ cursor,
                        const unsigned* __restrict__ packed, int* __restrict__ perm) {
    int b = blockIdx.x * 256 + threadIdx.x;
    int c = hist[b];
    if (c < 2) return;
    int s = cursor[b];
    for (int i = 1; i < c; i++) {
        int pj = perm[s + i];
        unsigned long long kj =
            ((unsigned long long)(packed[pj] >> 9) << 19) | (unsigned)pj;
        int m = i - 1;
        while (m >= 0) {
            int pm = perm[s + m];
            unsigned long long km =
                ((unsigned long long)(packed[pm] >> 9) << 19) | (unsigned)pm;
            if (km <= kj) break;
            perm[s + m + 1] = pm;
            m--;
        }
        perm[s + m + 1] = pj;
    }
}

// zeros + new_idx=-1 for invalid rows (nt stores); builds vlist of valid
// positions with ONE vcount atomic per block.
__global__ __launch_bounds__(256) void k_finalize(
    const int* __restrict__ perm, const unsigned* __restrict__ packed,
    int* __restrict__ vlist, int* __restrict__ vcount, float* __restrict__ out) {
    __shared__ int swoff[4];
    __shared__ int sbase;
    int tid = threadIdx.x;
    int w = tid >> 6, lane = tid & 63;
    int r0 = blockIdx.x * 128 + w * 32;
    int r = r0 + (lane & 31);
    bool lt32 = lane < 32;
    bool valid = false, inval = false;
    if (lt32) {
        int j = perm[r];
        unsigned lin = packed[j] >> 9;
        valid = ((lin & 0x201u) == 0u);
        inval = !valid;
    }
    unsigned long long bv = __ballot(valid);   // bits 0..31 only
    if (lane == 0) swoff[w] = __builtin_popcountll(bv);
    __syncthreads();
    if (tid == 0) {
        int c0 = swoff[0], c1 = swoff[1], c2 = swoff[2], c3 = swoff[3];
        sbase = atomicAdd(vcount, c0 + c1 + c2 + c3);
        swoff[0] = 0; swoff[1] = c0; swoff[2] = c0 + c1; swoff[3] = c0 + c1 + c2;
    }
    __syncthreads();
    if (valid) {
        int myoff = __builtin_popcountll(bv & ((1ull << lane) - 1ull));
        vlist[sbase + swoff[w] + myoff] = r;
    }
    if (lt32 && inval) {
        f32x4 mi = {-1.f, -1.f, -1.f, -1.f};
        nt_store4(&out[(size_t)N_VOX * COUT + (size_t)r * 4], mi);
    }
    unsigned long long bi = __ballot(inval);
    f32x4 z = {0.f, 0.f, 0.f, 0.f};
    // two rows per iteration: lanes 0-31 row l, lanes 32-63 row l+1
    #pragma unroll
    for (int l = 0; l < 32; l += 2) {
        int lr = l + (lane >> 5);
        if ((bi >> lr) & 1ull) {
            nt_store4(&out[(size_t)(r0 + lr) * COUT + (lane & 31) * 4], z);
        }
    }
}

// GEMM + LN for valid rows only. 512 thr, 8 waves x 16 rows = 128 rows/block.
__global__ __launch_bounds__(512) void k_valid(
    const float* __restrict__ feats, const float* __restrict__ weight,
    const float* __restrict__ gamma, const float* __restrict__ beta,
    const int* __restrict__ perm, const unsigned* __restrict__ packed,
    const int* __restrict__ vlist, const int* __restrict__ vcount,
    float* __restrict__ out) {
    __shared__ float Wlds[CIN][COUT];       // 32 KB
    __shared__ float featb[8][16][CIN];     // 32 KB (wave-private slices)
    int tid = threadIdx.x;
    int vc = *vcount;
    if ((int)blockIdx.x * 128 >= vc) return;

    #pragma unroll
    for (int i = 0; i < 4; i++) {
        int e = tid + i * 512;
        *(float4*)&((float*)Wlds)[e * 4] = *(const float4*)&weight[e * 4];
    }
    __syncthreads();

    int w = tid >> 6, lane = tid & 63;
    float2 gv = *(const float2*)&gamma[lane * 2];
    float2 bvv = *(const float2*)&beta[lane * 2];

    for (int mb = blockIdx.x * 128; mb < vc; mb += gridDim.x * 128) {
        int mrow = mb + w * 16;
        #pragma unroll
        for (int i = 0; i < 16; i++) {
            int m = mrow + i;
            int pos = (m < vc) ? vlist[m] : vlist[mb];
            int j = perm[pos];
            featb[w][i][lane] = feats[(size_t)j * CIN + lane];
        }

        float2 acc[16];
        #pragma unroll
        for (int i = 0; i < 16; i++) { acc[i].x = 0.f; acc[i].y = 0.f; }

        #pragma unroll 4
        for (int k0 = 0; k0 < CIN; k0 += 4) {
            float2 wv0 = *(float2*)&Wlds[k0 + 0][lane * 2];
            float2 wv1 = *(float2*)&Wlds[k0 + 1][lane * 2];
            float2 wv2 = *(float2*)&Wlds[k0 + 2][lane * 2];
            float2 wv3 = *(float2*)&Wlds[k0 + 3][lane * 2];
            #pragma unroll
            for (int i = 0; i < 16; i++) {
                float4 f = *(float4*)&featb[w][i][k0];
                acc[i].x = fmaf(f.x, wv0.x, acc[i].x); acc[i].y = fmaf(f.x, wv0.y, acc[i].y);
                acc[i].x = fmaf(f.y, wv1.x, acc[i].x); acc[i].y = fmaf(f.y, wv1.y, acc[i].y);
                acc[i].x = fmaf(f.z, wv2.x, acc[i].x); acc[i].y = fmaf(f.z, wv2.y, acc[i].y);
                acc[i].x = fmaf(f.w, wv3.x, acc[i].x); acc[i].y = fmaf(f.w, wv3.y, acc[i].y);
            }
        }

        #pragma unroll
        for (int i = 0; i < 16; i++) {
            int m = mrow + i;
            float v0 = acc[i].x, v1 = acc[i].y;
            float s = v0 + v1;
            float sq = v0 * v0 + v1 * v1;
            #pragma unroll
            for (int off = 32; off > 0; off >>= 1) {
                s  += __shfl_xor(s, off);
                sq += __shfl_xor(sq, off);
            }
            float mean = s * (1.0f / COUT);
            float var  = fmaxf(sq * (1.0f / COUT) - mean * mean, 0.0f);
            float rstd = rsqrtf(var + EPSV);
            if (m < vc) {                       // wave-uniform
                int pos = vlist[m];
                int j = perm[pos];
                unsigned lin = packed[j] >> 9;
                f32x2 o;
                o.x = (v0 - mean) * rstd * gv.x + bvv.x;
                o.y = (v1 - mean) * rstd * gv.y + bvv.y;
                nt_store2(&out[(size_t)pos * COUT + lane * 2], o);
                if (lane == 0) {
                    f32x4 ni;
                    ni.x = (float)(lin >> 21);
                    ni.y = (float)((lin >> 18) & 7u);
                    ni.z = (float)(((lin >> 9) & 511u) >> 1);
                    ni.w = (float)((lin & 511u) >> 1);
                    nt_store4(&out[(size_t)N_VOX * COUT + (size_t)pos * 4], ni);
                }
            }
        }
    }
}

extern "C" void kernel_launch(void* const* d_in, const int* in_sizes, int n_in,
                              void* d_out, int out_size, void* d_ws, size_t ws_size,
                              hipStream_t stream) {
    const float* feats  = (const float*)d_in[0];
    const int*   idx    = (const int*)d_in[1];
    const float* weight = (const float*)d_in[2];
    const float* gamma  = (const float*)d_in[3];
    const float* beta   = (const float*)d_in[4];
    float* out = (float*)d_out;

    int* ws = (int*)d_ws;
    int*      hist     = ws;                            // BINS
    int*      vcount   = ws + BINS;                     // 1 (+3 pad)
    int*      cursor   = ws + BINS + 4;                 // BINS
    unsigned* packed   = (unsigned*)(ws + 2 * BINS + 4);// N
    int*      perm     = ws + 2 * BINS + 4 + N_VOX;     // N
    int*      vlist    = ws + 2 * BINS + 4 + 2 * N_VOX; // N
    int*      partials = ws + 2 * BINS + 4 + 3 * N_VOX; // 128

    k_clear<<<(BINS / 4 + 1 + 255) / 256 + 1, 256, 0, stream>>>(hist);
    k_hist<<<N_VOX / 256, 256, 0, stream>>>(idx, packed, hist);
    scan_partial<<<BINS / 1024, 256, 0, stream>>>(hist, partials);
    scan_top<<<1, 128, 0, stream>>>(partials);
    scan_final<<<BINS / 1024, 256, 0, stream>>>(hist, partials, cursor);
    k_scatter<<<N_VOX / 256, 256, 0, stream>>>(packed, cursor, perm);
    k_fixup<<<BINS / 256, 256, 0, stream>>>(hist, cursor, packed, perm);
    k_finalize<<<N_VOX / 128, 256, 0, stream>>>(perm, packed, vlist, vcount, out);
    k_valid<<<1024, 512, 0, stream>>>(feats, weight, gamma, beta,
                                      perm, packed, vlist, vcount, out);
}

// Round 7
// 179.710 us; speedup vs baseline: 1.2480x; 1.2480x over previous
//
#include <hip/hip_runtime.h>
#include <stdint.h>

#define N_VOX   (1 << 19)
#define CIN     64
#define COUT    128
#define BIN_SHIFT 3
#define BINS    (1 << 20)          // (4*8*512*512) >> 3, lambda = 0.5/bin
#define OFF_BITS 4                 // intra-bin arrival offset, max ~8 << 16
#define BPB     256                // bins per k_mega block (~128 positions)
#define EPSV    1e-5f

typedef float f32x4 __attribute__((ext_vector_type(4)));
typedef float f32x2 __attribute__((ext_vector_type(2)));

static __device__ __forceinline__ void nt_store4(float* p, f32x4 v) {
    __builtin_nontemporal_store(v, (f32x4*)p);
}
static __device__ __forceinline__ void nt_store2(float* p, f32x2 v) {
    __builtin_nontemporal_store(v, (f32x2*)p);
}

// d_out: out_f [N,128] f32 | new_idx [N,4] f32.
// valid row <=> (lin & 0x201)==0. lin = b<<21 | t<<18 | y<<9 | x.
// ws ints: hist[BINS] | cursor[BINS] | packed[N] | perm[N] | partials[1024]

__global__ void k_clear(int* __restrict__ p) {
    int t = blockIdx.x * 256 + threadIdx.x;   // 1024*256*4 == BINS exactly
    *(int4*)&p[t * 4] = make_int4(0, 0, 0, 0);
}

__global__ void k_hist(const int* __restrict__ idx, unsigned* __restrict__ packed,
                       int* __restrict__ hist) {
    int j = blockIdx.x * 256 + threadIdx.x;
    int4 v = *(const int4*)&idx[j * 4];
    int lin = ((v.x * 8 + v.y) * 512 + v.z) * 512 + v.w;
    int off = atomicAdd(&hist[lin >> BIN_SHIFT], 1);
    packed[j] = ((unsigned)lin << OFF_BITS) | (unsigned)off;
}

// 1024 blocks x 256 thr: block sums 1024 bins -> partials[1024]
__global__ void scan_partial(const int* __restrict__ hist, int* __restrict__ partials) {
    __shared__ int sdata[256];
    int base = blockIdx.x * 1024;
    int t = threadIdx.x;
    int s = hist[base + t] + hist[base + t + 256] + hist[base + t + 512] + hist[base + t + 768];
    sdata[t] = s;
    __syncthreads();
    for (int off = 128; off > 0; off >>= 1) {
        if (t < off) sdata[t] += sdata[t + off];
        __syncthreads();
    }
    if (t == 0) partials[blockIdx.x] = sdata[0];
}

// 1 block x 1024 thr: exclusive scan of partials[1024]
__global__ void scan_top(int* __restrict__ partials) {
    __shared__ int sdata[1024];
    int t = threadIdx.x;
    sdata[t] = partials[t];
    __syncthreads();
    for (int off = 1; off < 1024; off <<= 1) {
        int v = 0;
        if (t >= off) v = sdata[t - off];
        __syncthreads();
        sdata[t] += v;
        __syncthreads();
    }
    partials[t] = t ? sdata[t - 1] : 0;
}

// 1024 blocks x 256 thr: per-block scan of 1024 bins + block prefix
__global__ void scan_final(const int* __restrict__ hist, const int* __restrict__ partials,
                           int* __restrict__ cursor) {
    __shared__ int sscan[256];
    int t = threadIdx.x;
    int base = blockIdx.x * 1024 + t * 4;
    int4 v = *(const int4*)&hist[base];
    int s0 = v.x, s1 = v.x + v.y, s2 = s1 + v.z, s3 = s2 + v.w;
    sscan[t] = s3;
    __syncthreads();
    for (int off = 1; off < 256; off <<= 1) {
        int u = 0;
        if (t >= off) u = sscan[t - off];
        __syncthreads();
        sscan[t] += u;
        __syncthreads();
    }
    int prefix = partials[blockIdx.x] + (t ? sscan[t - 1] : 0);
    int4 e;
    e.x = prefix;
    e.y = prefix + s0;
    e.z = prefix + s1;
    e.w = prefix + s2;
    *(int4*)&cursor[base] = e;   // cursor = bin start, read-only afterwards
}

__global__ void k_scatter(const unsigned* __restrict__ packed, const int* __restrict__ cursor,
                          int* __restrict__ perm) {
    int j = blockIdx.x * 256 + threadIdx.x;
    unsigned p = packed[j];
    int pos = cursor[p >> (OFF_BITS + BIN_SHIFT)] + (int)(p & ((1u << OFF_BITS) - 1u));
    perm[pos] = j;
}

// ---------- fused fixup + finalize + GEMM + LN ----------
// block owns bins [B0, B0+256) => positions [cursor[B0], cursor[B0+256)).
// Phase A: thread-per-bin stable fixup + validity classify (block-local scan,
//          no global atomics). Phase B: zeros + (-1) idx for invalid rows.
// Phase C: GEMM+LN for valid rows (4 waves x 8 rows per sweep).
__global__ __launch_bounds__(256) void k_mega(
    const float* __restrict__ feats, const float* __restrict__ weight,
    const float* __restrict__ gamma, const float* __restrict__ beta,
    const int* __restrict__ hist, const int* __restrict__ cursor,
    const unsigned* __restrict__ packed, int* __restrict__ perm,
    float* __restrict__ out) {
    __shared__ float Wlds[CIN][COUT];          // 32 KB
    __shared__ float featb[4][8][CIN];         // 8 KB
    __shared__ int sscan[256];
    __shared__ unsigned ibit[32];              // 1024-position invalid bitmap
    __shared__ unsigned short vpos[256];       // local offsets of valid rows
    __shared__ int snv;

    int tid = threadIdx.x;
    int B0 = blockIdx.x * BPB;
    int p0 = cursor[B0];
    int p1 = (B0 + BPB < BINS) ? cursor[B0 + BPB] : N_VOX;
    int npos = p1 - p0;                        // ~Poisson(128)

    #pragma unroll
    for (int i = 0; i < 8; i++) {
        int e = tid + i * 256;
        *(float4*)&((float*)Wlds)[e * 4] = *(const float4*)&weight[e * 4];
    }
    if (tid < 32) ibit[tid] = 0;

    // Phase A: per-bin stable fixup (key = lin<<19 | j), validity count
    int b = B0 + tid;
    int c = hist[b];
    int s = cursor[b];
    if (c >= 2) {
        for (int i = 1; i < c; i++) {
            int pj = perm[s + i];
            unsigned long long kj =
                ((unsigned long long)(packed[pj] >> OFF_BITS) << 19) | (unsigned)pj;
            int m = i - 1;
            while (m >= 0) {
                int pm = perm[s + m];
                unsigned long long km =
                    ((unsigned long long)(packed[pm] >> OFF_BITS) << 19) | (unsigned)pm;
                if (km <= kj) break;
                perm[s + m + 1] = pm;
                m--;
            }
            perm[s + m + 1] = pj;
        }
    }
    int myv = 0;
    for (int i = 0; i < c; i++) {
        unsigned lin = packed[perm[s + i]] >> OFF_BITS;
        myv += ((lin & 0x201u) == 0u) ? 1 : 0;
    }
    sscan[tid] = myv;
    __syncthreads();
    for (int off = 1; off < 256; off <<= 1) {
        int u = 0;
        if (tid >= off) u = sscan[tid - off];
        __syncthreads();
        sscan[tid] += u;
        __syncthreads();
    }
    if (tid == 255) snv = sscan[255];
    int basev = sscan[tid] - myv;
    for (int i = 0; i < c; i++) {
        int pos = s + i;
        unsigned lin = packed[perm[pos]] >> OFF_BITS;
        int lp = pos - p0;
        if ((lin & 0x201u) == 0u) vpos[basev++] = (unsigned short)lp;
        else atomicOr(&ibit[lp >> 5], 1u << (lp & 31));
    }
    __syncthreads();

    int w = tid >> 6, lane = tid & 63;

    // Phase B: invalid rows -> new_idx = -1 (coalesced), zero feature rows
    {
        f32x4 mi = {-1.f, -1.f, -1.f, -1.f};
        for (int lp = tid; lp < npos; lp += 256) {
            if ((ibit[lp >> 5] >> (lp & 31)) & 1u)
                nt_store4(&out[(size_t)N_VOX * COUT + (size_t)(p0 + lp) * 4], mi);
        }
        f32x4 z = {0.f, 0.f, 0.f, 0.f};
        for (int lp = w * 2 + (lane >> 5); lp < npos; lp += 8) {
            if ((ibit[lp >> 5] >> (lp & 31)) & 1u)
                nt_store4(&out[(size_t)(p0 + lp) * COUT + (lane & 31) * 4], z);
        }
    }

    // Phase C: GEMM + LN for valid rows
    int nv = snv;
    if (nv == 0) return;
    float2 gv = *(const float2*)&gamma[lane * 2];
    float2 bvv = *(const float2*)&beta[lane * 2];

    for (int m0 = 0; m0 < nv; m0 += 32) {
        int mb = m0 + w * 8;
        if (mb >= nv) continue;                 // no barriers below: safe
        int jr[8], pr[8];
        #pragma unroll
        for (int i = 0; i < 8; i++) {
            int m = mb + i;
            int pos = p0 + vpos[(m < nv) ? m : 0];
            int j = perm[pos];
            jr[i] = j; pr[i] = pos;
            featb[w][i][lane] = feats[(size_t)j * CIN + lane];
        }

        float2 acc[8];
        #pragma unroll
        for (int i = 0; i < 8; i++) { acc[i].x = 0.f; acc[i].y = 0.f; }

        #pragma unroll 4
        for (int k0 = 0; k0 < CIN; k0 += 4) {
            float2 wv0 = *(float2*)&Wlds[k0 + 0][lane * 2];
            float2 wv1 = *(float2*)&Wlds[k0 + 1][lane * 2];
            float2 wv2 = *(float2*)&Wlds[k0 + 2][lane * 2];
            float2 wv3 = *(float2*)&Wlds[k0 + 3][lane * 2];
            #pragma unroll
            for (int i = 0; i < 8; i++) {
                float4 f = *(float4*)&featb[w][i][k0];
                acc[i].x = fmaf(f.x, wv0.x, acc[i].x); acc[i].y = fmaf(f.x, wv0.y, acc[i].y);
                acc[i].x = fmaf(f.y, wv1.x, acc[i].x); acc[i].y = fmaf(f.y, wv1.y, acc[i].y);
                acc[i].x = fmaf(f.z, wv2.x, acc[i].x); acc[i].y = fmaf(f.z, wv2.y, acc[i].y);
                acc[i].x = fmaf(f.w, wv3.x, acc[i].x); acc[i].y = fmaf(f.w, wv3.y, acc[i].y);
            }
        }

        #pragma unroll
        for (int i = 0; i < 8; i++) {
            int m = mb + i;
            float v0 = acc[i].x, v1 = acc[i].y;
            float sm = v0 + v1;
            float sq = v0 * v0 + v1 * v1;
            #pragma unroll
            for (int off = 32; off > 0; off >>= 1) {
                sm += __shfl_xor(sm, off);
                sq += __shfl_xor(sq, off);
            }
            float mean = sm * (1.0f / COUT);
            float var  = fmaxf(sq * (1.0f / COUT) - mean * mean, 0.0f);
            float rstd = rsqrtf(var + EPSV);
            if (m < nv) {
                int pos = pr[i];
                f32x2 o;
                o.x = (v0 - mean) * rstd * gv.x + bvv.x;
                o.y = (v1 - mean) * rstd * gv.y + bvv.y;
                nt_store2(&out[(size_t)pos * COUT + lane * 2], o);
                if (lane == 0) {
                    unsigned lin = packed[jr[i]] >> OFF_BITS;
                    f32x4 ni;
                    ni.x = (float)(lin >> 21);
                    ni.y = (float)((lin >> 18) & 7u);
                    ni.z = (float)(((lin >> 9) & 511u) >> 1);
                    ni.w = (float)((lin & 511u) >> 1);
                    nt_store4(&out[(size_t)N_VOX * COUT + (size_t)pos * 4], ni);
                }
            }
        }
    }
}

extern "C" void kernel_launch(void* const* d_in, const int* in_sizes, int n_in,
                              void* d_out, int out_size, void* d_ws, size_t ws_size,
                              hipStream_t stream) {
    const float* feats  = (const float*)d_in[0];
    const int*   idx    = (const int*)d_in[1];
    const float* weight = (const float*)d_in[2];
    const float* gamma  = (const float*)d_in[3];
    const float* beta   = (const float*)d_in[4];
    float* out = (float*)d_out;

    int* ws = (int*)d_ws;
    int*      hist     = ws;                        // BINS
    int*      cursor   = ws + BINS;                 // BINS
    unsigned* packed   = (unsigned*)(ws + 2 * BINS);// N
    int*      perm     = ws + 2 * BINS + N_VOX;     // N
    int*      partials = ws + 2 * BINS + 2 * N_VOX; // 1024

    k_clear<<<BINS / 1024, 256, 0, stream>>>(hist);
    k_hist<<<N_VOX / 256, 256, 0, stream>>>(idx, packed, hist);
    scan_partial<<<BINS / 1024, 256, 0, stream>>>(hist, partials);
    scan_top<<<1, 1024, 0, stream>>>(partials);
    scan_final<<<BINS / 1024, 256, 0, stream>>>(hist, partials, cursor);
    k_scatter<<<N_VOX / 256, 256, 0, stream>>>(packed, cursor, perm);
    k_mega<<<BINS / BPB, 256, 0, stream>>>(feats, weight, gamma, beta,
                                           hist, cursor, packed, perm, out);
}

// Round 8
// 168.348 us; speedup vs baseline: 1.3323x; 1.0675x over previous
//
#include <hip/hip_runtime.h>
#include <stdint.h>

#define N_VOX   (1 << 19)
#define CIN     64
#define COUT    128
#define BIN_SHIFT 3
#define BINS    (1 << 20)          // (4*8*512*512) >> 3, lambda = 0.5/bin
#define OFF_BITS 4                 // intra-bin arrival offset
#define BPB     256                // bins per k_mega block (~128 positions)
#define EPSV    1e-5f

typedef float f32x4 __attribute__((ext_vector_type(4)));
typedef float f32x2 __attribute__((ext_vector_type(2)));

static __device__ __forceinline__ void nt_store4(float* p, f32x4 v) {
    __builtin_nontemporal_store(v, (f32x4*)p);
}
static __device__ __forceinline__ void nt_store2(float* p, f32x2 v) {
    __builtin_nontemporal_store(v, (f32x2*)p);
}

// d_out: out_f [N,128] f32 | new_idx [N,4] f32.
// valid row <=> (lin & 0x201)==0. lin = b<<21 | t<<18 | y<<9 | x.
// ws ints: hist[BINS] | cursor[BINS] | packed[N] | perm[N] | partials[1024]

__global__ void k_clear(int* __restrict__ p) {
    int t = blockIdx.x * 256 + threadIdx.x;   // 1024*256*4 == BINS exactly
    *(int4*)&p[t * 4] = make_int4(0, 0, 0, 0);
}

__global__ void k_hist(const int* __restrict__ idx, unsigned* __restrict__ packed,
                       int* __restrict__ hist) {
    int j = blockIdx.x * 256 + threadIdx.x;
    int4 v = *(const int4*)&idx[j * 4];
    int lin = ((v.x * 8 + v.y) * 512 + v.z) * 512 + v.w;
    int off = atomicAdd(&hist[lin >> BIN_SHIFT], 1);
    packed[j] = ((unsigned)lin << OFF_BITS) | (unsigned)off;
}

__global__ void scan_partial(const int* __restrict__ hist, int* __restrict__ partials) {
    __shared__ int sdata[256];
    int base = blockIdx.x * 1024;
    int t = threadIdx.x;
    int s = hist[base + t] + hist[base + t + 256] + hist[base + t + 512] + hist[base + t + 768];
    sdata[t] = s;
    __syncthreads();
    for (int off = 128; off > 0; off >>= 1) {
        if (t < off) sdata[t] += sdata[t + off];
        __syncthreads();
    }
    if (t == 0) partials[blockIdx.x] = sdata[0];
}

__global__ void scan_top(int* __restrict__ partials) {
    __shared__ int sdata[1024];
    int t = threadIdx.x;
    sdata[t] = partials[t];
    __syncthreads();
    for (int off = 1; off < 1024; off <<= 1) {
        int v = 0;
        if (t >= off) v = sdata[t - off];
        __syncthreads();
        sdata[t] += v;
        __syncthreads();
    }
    partials[t] = t ? sdata[t - 1] : 0;
}

__global__ void scan_final(const int* __restrict__ hist, const int* __restrict__ partials,
                           int* __restrict__ cursor) {
    __shared__ int sscan[256];
    int t = threadIdx.x;
    int base = blockIdx.x * 1024 + t * 4;
    int4 v = *(const int4*)&hist[base];
    int s0 = v.x, s1 = v.x + v.y, s2 = s1 + v.z, s3 = s2 + v.w;
    sscan[t] = s3;
    __syncthreads();
    for (int off = 1; off < 256; off <<= 1) {
        int u = 0;
        if (t >= off) u = sscan[t - off];
        __syncthreads();
        sscan[t] += u;
        __syncthreads();
    }
    int prefix = partials[blockIdx.x] + (t ? sscan[t - 1] : 0);
    int4 e;
    e.x = prefix;
    e.y = prefix + s0;
    e.z = prefix + s1;
    e.w = prefix + s2;
    *(int4*)&cursor[base] = e;   // cursor = bin start, read-only afterwards
}

__global__ void k_scatter(const unsigned* __restrict__ packed, const int* __restrict__ cursor,
                          int* __restrict__ perm) {
    int j = blockIdx.x * 256 + threadIdx.x;
    unsigned p = packed[j];
    int pos = cursor[p >> (OFF_BITS + BIN_SHIFT)] + (int)(p & ((1u << OFF_BITS) - 1u));
    perm[pos] = j;
}

// ---------- fused fixup + finalize + GEMM + LN ----------
// LDS-lean version: W read from global (L1/L2-resident 32 KB), wave-shuffle
// scan (1 barrier). LDS ~9 KB -> occupancy thread/VGPR-limited, not LDS.
__global__ __launch_bounds__(256) void k_mega(
    const float* __restrict__ feats, const float* __restrict__ weight,
    const float* __restrict__ gamma, const float* __restrict__ beta,
    const int* __restrict__ hist, const int* __restrict__ cursor,
    const unsigned* __restrict__ packed, int* __restrict__ perm,
    float* __restrict__ out) {
    __shared__ float featb[4][8][CIN];         // 8 KB (wave-private slices)
    __shared__ int wsum[4];
    __shared__ unsigned ibit[32];              // 1024-position invalid bitmap
    __shared__ unsigned short vpos[384];       // local offsets of valid rows

    int tid = threadIdx.x;
    int w = tid >> 6, lane = tid & 63;
    int B0 = blockIdx.x * BPB;
    int p0 = cursor[B0];
    int p1 = (B0 + BPB < BINS) ? cursor[B0 + BPB] : N_VOX;
    int npos = p1 - p0;                        // ~Poisson(128)

    if (tid < 32) ibit[tid] = 0;

    // Phase A: per-bin stable fixup (key = lin<<19 | j) + validity
    int b = B0 + tid;
    int c = hist[b];
    int s = cursor[b];
    if (c >= 2) {
        for (int i = 1; i < c; i++) {
            int pj = perm[s + i];
            unsigned long long kj =
                ((unsigned long long)(packed[pj] >> OFF_BITS) << 19) | (unsigned)pj;
            int m = i - 1;
            while (m >= 0) {
                int pm = perm[s + m];
                unsigned long long km =
                    ((unsigned long long)(packed[pm] >> OFF_BITS) << 19) | (unsigned)pm;
                if (km <= kj) break;
                perm[s + m + 1] = pm;
                m--;
            }
            perm[s + m + 1] = pj;
        }
    }
    int myv = 0;
    for (int i = 0; i < c; i++) {
        unsigned lin = packed[perm[s + i]] >> OFF_BITS;
        myv += ((lin & 0x201u) == 0u) ? 1 : 0;
    }
    // wave inclusive scan of myv
    int incl = myv;
    #pragma unroll
    for (int off = 1; off < 64; off <<= 1) {
        int u = __shfl_up(incl, off);
        if (lane >= off) incl += u;
    }
    if (lane == 63) wsum[w] = incl;
    __syncthreads();
    int s0 = wsum[0], s1 = wsum[1], s2 = wsum[2], s3 = wsum[3];
    int nv = s0 + s1 + s2 + s3;
    int woff = (w > 0 ? s0 : 0) + (w > 1 ? s1 : 0) + (w > 2 ? s2 : 0);
    int basev = woff + incl - myv;
    for (int i = 0; i < c; i++) {
        int pos = s + i;
        unsigned lin = packed[perm[pos]] >> OFF_BITS;
        int lp = pos - p0;
        if ((lin & 0x201u) == 0u) vpos[basev++] = (unsigned short)lp;
        else atomicOr(&ibit[lp >> 5], 1u << (lp & 31));
    }
    __syncthreads();

    // Phase B: invalid rows -> new_idx = -1, zero feature rows (nt stores)
    {
        f32x4 mi = {-1.f, -1.f, -1.f, -1.f};
        for (int lp = tid; lp < npos; lp += 256) {
            if ((ibit[lp >> 5] >> (lp & 31)) & 1u)
                nt_store4(&out[(size_t)N_VOX * COUT + (size_t)(p0 + lp) * 4], mi);
        }
        f32x4 z = {0.f, 0.f, 0.f, 0.f};
        for (int lp = w * 2 + (lane >> 5); lp < npos; lp += 8) {
            if ((ibit[lp >> 5] >> (lp & 31)) & 1u)
                nt_store4(&out[(size_t)(p0 + lp) * COUT + (lane & 31) * 4], z);
        }
    }

    // Phase C: GEMM + LN for valid rows (W from global: L1/L2-resident)
    if (nv == 0) return;
    const float2* Wg = (const float2*)weight;
    float2 gv = *(const float2*)&gamma[lane * 2];
    float2 bvv = *(const float2*)&beta[lane * 2];

    for (int m0 = 0; m0 < nv; m0 += 32) {
        int mb = m0 + w * 8;
        if (mb >= nv) continue;                 // no barriers below: safe
        #pragma unroll
        for (int i = 0; i < 8; i++) {
            int m = mb + i;
            int pos = p0 + vpos[(m < nv) ? m : 0];
            featb[w][i][lane] = feats[(size_t)perm[pos] * CIN + lane];
        }

        float2 acc[8];
        #pragma unroll
        for (int i = 0; i < 8; i++) { acc[i].x = 0.f; acc[i].y = 0.f; }

        #pragma unroll 4
        for (int k0 = 0; k0 < CIN; k0 += 4) {
            float2 wv0 = Wg[(k0 + 0) * 64 + lane];
            float2 wv1 = Wg[(k0 + 1) * 64 + lane];
            float2 wv2 = Wg[(k0 + 2) * 64 + lane];
            float2 wv3 = Wg[(k0 + 3) * 64 + lane];
            #pragma unroll
            for (int i = 0; i < 8; i++) {
                float4 f = *(float4*)&featb[w][i][k0];
                acc[i].x = fmaf(f.x, wv0.x, acc[i].x); acc[i].y = fmaf(f.x, wv0.y, acc[i].y);
                acc[i].x = fmaf(f.y, wv1.x, acc[i].x); acc[i].y = fmaf(f.y, wv1.y, acc[i].y);
                acc[i].x = fmaf(f.z, wv2.x, acc[i].x); acc[i].y = fmaf(f.z, wv2.y, acc[i].y);
                acc[i].x = fmaf(f.w, wv3.x, acc[i].x); acc[i].y = fmaf(f.w, wv3.y, acc[i].y);
            }
        }

        #pragma unroll
        for (int i = 0; i < 8; i++) {
            int m = mb + i;
            float v0 = acc[i].x, v1 = acc[i].y;
            float sm = v0 + v1;
            float sq = v0 * v0 + v1 * v1;
            #pragma unroll
            for (int off = 32; off > 0; off >>= 1) {
                sm += __shfl_xor(sm, off);
                sq += __shfl_xor(sq, off);
            }
            float mean = sm * (1.0f / COUT);
            float var  = fmaxf(sq * (1.0f / COUT) - mean * mean, 0.0f);
            float rstd = rsqrtf(var + EPSV);
            if (m < nv) {
                int pos = p0 + vpos[m];
                f32x2 o;
                o.x = (v0 - mean) * rstd * gv.x + bvv.x;
                o.y = (v1 - mean) * rstd * gv.y + bvv.y;
                nt_store2(&out[(size_t)pos * COUT + lane * 2], o);
                if (lane == 0) {
                    unsigned lin = packed[perm[pos]] >> OFF_BITS;
                    f32x4 ni;
                    ni.x = (float)(lin >> 21);
                    ni.y = (float)((lin >> 18) & 7u);
                    ni.z = (float)(((lin >> 9) & 511u) >> 1);
                    ni.w = (float)((lin & 511u) >> 1);
                    nt_store4(&out[(size_t)N_VOX * COUT + (size_t)pos * 4], ni);
                }
            }
        }
    }
}

extern "C" void kernel_launch(void* const* d_in, const int* in_sizes, int n_in,
                              void* d_out, int out_size, void* d_ws, size_t ws_size,
                              hipStream_t stream) {
    const float* feats  = (const float*)d_in[0];
    const int*   idx    = (const int*)d_in[1];
    const float* weight = (const float*)d_in[2];
    const float* gamma  = (const float*)d_in[3];
    const float* beta   = (const float*)d_in[4];
    float* out = (float*)d_out;

    int* ws = (int*)d_ws;
    int*      hist     = ws;                        // BINS
    int*      cursor   = ws + BINS;                 // BINS
    unsigned* packed   = (unsigned*)(ws + 2 * BINS);// N
    int*      perm     = ws + 2 * BINS + N_VOX;     // N
    int*      partials = ws + 2 * BINS + 2 * N_VOX; // 1024

    k_clear<<<BINS / 1024, 256, 0, stream>>>(hist);
    k_hist<<<N_VOX / 256, 256, 0, stream>>>(idx, packed, hist);
    scan_partial<<<BINS / 1024, 256, 0, stream>>>(hist, partials);
    scan_top<<<1, 1024, 0, stream>>>(partials);
    scan_final<<<BINS / 1024, 256, 0, stream>>>(hist, partials, cursor);
    k_scatter<<<N_VOX / 256, 256, 0, stream>>>(packed, cursor, perm);
    k_mega<<<BINS / BPB, 256, 0, stream>>>(feats, weight, gamma, beta,
                                           hist, cursor, packed, perm, out);
}